// Round 15
// baseline (93.061 us; speedup 1.0000x reference)
//
#include <hip/hip_runtime.h>
#include <hip/hip_bf16.h>

typedef __bf16 bf16_t;
typedef __bf16 bf16x8 __attribute__((ext_vector_type(8)));
typedef __bf16 bf16x4 __attribute__((ext_vector_type(4)));
typedef float  f32x4  __attribute__((ext_vector_type(4)));
typedef unsigned int u32x4 __attribute__((ext_vector_type(4)));

#define MFMA16(a,b,c) __builtin_amdgcn_mfma_f32_16x16x32_bf16(a,b,c,0,0,0)

constexpr int B_ = 2, T_ = 2048, H_ = 16, D_ = 64, C_ = 1024;
constexpr int GK = C_;          // GEMM K dim (1024)

// async global->LDS, 16B per lane. LDS dest: wave-uniform base + lane*16.
typedef const __attribute__((address_space(1))) unsigned char ga_t;
typedef __attribute__((address_space(3))) unsigned char la_t;
__device__ __forceinline__ void gld16(const void* g, void* l) {
  __builtin_amdgcn_global_load_lds((ga_t*)g, (la_t*)l, 16, 0, 0);
}

// ---------------- cast fp32 -> bf16 (X, Wq, Wk, Wv, Wp) ----------------
__global__ __launch_bounds__(256) void cast_all(
    const float* __restrict__ X,  const float* __restrict__ Wq,
    const float* __restrict__ Wk, const float* __restrict__ Wv,
    const float* __restrict__ Wp,
    bf16_t* __restrict__ Xb,  bf16_t* __restrict__ Wqb, bf16_t* __restrict__ Wkb,
    bf16_t* __restrict__ Wvb, bf16_t* __restrict__ Wpb)
{
  int i = blockIdx.x * 256 + threadIdx.x;   // each thread converts 4 floats
  const float* src; bf16_t* dst; int off;
  if      (i < 1048576) { src = X;  dst = Xb;  off = i; }
  else if (i < 1310720) { src = Wq; dst = Wqb; off = i - 1048576; }
  else if (i < 1572864) { src = Wk; dst = Wkb; off = i - 1310720; }
  else if (i < 1835008) { src = Wv; dst = Wvb; off = i - 1572864; }
  else                  { src = Wp; dst = Wpb; off = i - 1835008; }
  float4 v = *reinterpret_cast<const float4*>(src + (size_t)off * 4);
  bf16x4 o;
  o[0] = (bf16_t)v.x; o[1] = (bf16_t)v.y; o[2] = (bf16_t)v.z; o[3] = (bf16_t)v.w;
  *reinterpret_cast<bf16x4*>(dst + (size_t)off * 4) = o;
}

// =============================================================================
// 2-phase 128x128 BK=64 counted-vmcnt GEMM core (R11 — best measured;
// kept verbatim for gemm_proj).
// =============================================================================
__device__ __forceinline__ void gemm128_core(
    const bf16_t* __restrict__ A, const bf16_t* __restrict__ Bw,
    bf16_t* sA, bf16_t* sB, f32x4 (&acc)[4][2], int bx, int by)
{
  const int tid = threadIdx.x, lane = tid & 63, wid = tid >> 6;
  const int wm = wid >> 2, wn = wid & 3;
  const int g = lane >> 4, c = lane & 15, rk = c & 7;
  const int srow = tid >> 3;                    // 0..63 rows per 64-row slab
  const int sg   = (tid & 7) ^ (srow & 7);      // pre-swizzled source granule
  const bf16_t* asrc = A  + (size_t)(bx * 128 + srow) * GK + sg * 8;
  const bf16_t* bsrc = Bw + (size_t)(by * 128 + srow) * GK + sg * 8;

  #define STGP(buf, kt)                                                       \
    { char* da = (char*)sA + (buf) * 16384;                                   \
      char* db = (char*)sB + (buf) * 16384;                                   \
      _Pragma("unroll")                                                       \
      for (int it = 0; it < 2; ++it) {                                        \
        gld16(asrc + (size_t)it * 65536 + (kt) * 64, da + (it * 512 + tid) * 16); \
        gld16(bsrc + (size_t)it * 65536 + (kt) * 64, db + (it * 512 + tid) * 16); \
      } }

  #define ITERP(t, buf)                                                       \
    {                                                                         \
      if ((t) < 15) asm volatile("s_waitcnt vmcnt(4)" ::: "memory");          \
      else          asm volatile("s_waitcnt vmcnt(0)" ::: "memory");          \
      __builtin_amdgcn_s_barrier();             /* buf[cur] ready */          \
      const char* ca = (const char*)sA + (buf) * 16384;                       \
      const char* cb = (const char*)sB + (buf) * 16384;                       \
      bf16x8 af[4][2], bfr[2][2];                                             \
      _Pragma("unroll")                                                       \
      for (int mi = 0; mi < 4; ++mi)                                          \
        _Pragma("unroll")                                                     \
        for (int ks = 0; ks < 2; ++ks)                                        \
          af[mi][ks] = *reinterpret_cast<const bf16x8*>(                      \
              ca + (wm * 64 + mi * 16 + c) * 128 + (((ks * 4 + g) ^ rk) * 16)); \
      _Pragma("unroll")                                                       \
      for (int ni = 0; ni < 2; ++ni)                                          \
        _Pragma("unroll")                                                     \
        for (int ks = 0; ks < 2; ++ks)                                        \
          bfr[ni][ks] = *reinterpret_cast<const bf16x8*>(                     \
              cb + (wn * 32 + ni * 16 + c) * 128 + (((ks * 4 + g) ^ rk) * 16)); \
      asm volatile("s_waitcnt lgkmcnt(0)" ::: "memory"); /* my reads done */  \
      __builtin_amdgcn_s_barrier();             /* all reads done */          \
      if ((t) + 2 < 16) STGP(buf, (t) + 2);     /* refill freed buffer */     \
      __builtin_amdgcn_s_setprio(1);                                          \
      _Pragma("unroll")                                                       \
      for (int ks = 0; ks < 2; ++ks)                                          \
        _Pragma("unroll")                                                     \
        for (int mi = 0; mi < 4; ++mi)                                        \
          _Pragma("unroll")                                                   \
          for (int ni = 0; ni < 2; ++ni)                                      \
            acc[mi][ni] = MFMA16(af[mi][ks], bfr[ni][ks], acc[mi][ni]);       \
      __builtin_amdgcn_s_setprio(0);                                          \
    }

  STGP(0, 0);                                   // prologue: 2 tiles in flight
  STGP(1, 1);
  #pragma unroll 1
  for (int t0 = 0; t0 < 16; t0 += 2) {
    ITERP(t0, 0);
    ITERP(t0 + 1, 1);
  }
  #undef ITERP
  #undef STGP
}

// ---------------- fused QKV projection: C[4096,3072] = Xb @ Wqkv^T -----------
// PERSISTENT 3-SEGMENT version of the R11 core (R14 post-mortem: remaining
// gap to m97's 874 TF at identical tile/staging is K-depth amortization —
// m97 ran 64 K-steps/block, we ran 16). Grid 32x8 = 256 blocks; each block
// keeps bx and sweeps seg = 0,1,2 (q,k,v col-segments) in ONE continuous
// 48-K-step pipeline: STG(tt+2) prefetch crosses segment boundaries (B addr
// += seg*1024*GK; A repeats every 16), eliminating 2 of 3 fills/drains.
// Inline epilogue at kt==15 per segment (mode = seg), then acc rezero.
__global__ __launch_bounds__(512, 2) void gemm_qkv(
    const bf16_t* __restrict__ Xb, const bf16_t* __restrict__ Wqkv,
    bf16_t* __restrict__ qo, bf16_t* __restrict__ ko, bf16_t* __restrict__ vto)
{
  __shared__ bf16_t sA[2][128 * 64];            // 32 KB
  __shared__ bf16_t sB[2][128 * 64];            // 32 KB
  const int tid = threadIdx.x, lane = tid & 63, wid = tid >> 6;
  const int wm = wid >> 2, wn = wid & 3;
  const int g = lane >> 4, c = lane & 15, rk = c & 7;
  const int bx = blockIdx.x, by = blockIdx.y;
  const int srow = tid >> 3;
  const int sg   = (tid & 7) ^ (srow & 7);
  const bf16_t* asrc = Xb   + (size_t)(bx * 128 + srow) * GK + sg * 8;
  const bf16_t* bsrc = Wqkv + (size_t)(by * 128 + srow) * GK + sg * 8;
  f32x4 acc[4][2] = {};
  const float qscale = 0.04508422002778f;       // log2(e) * 1024^-0.5

  // stage K-step tt (kt = tt&15, seg = tt>>4): 2 A-slabs + 2 B-slabs
  #define STGQ(buf, tt_)                                                      \
    { int kt_ = (tt_) & 15;                                                   \
      size_t sb_ = (size_t)((tt_) >> 4) * 1048576;                            \
      char* da = (char*)sA + (buf) * 16384;                                   \
      char* db = (char*)sB + (buf) * 16384;                                   \
      _Pragma("unroll")                                                       \
      for (int it = 0; it < 2; ++it) {                                        \
        gld16(asrc + (size_t)it * 65536 + kt_ * 64, da + (it * 512 + tid) * 16); \
        gld16(bsrc + sb_ + (size_t)it * 65536 + kt_ * 64, db + (it * 512 + tid) * 16); \
      } }

  // one K-step (WAITOP = counted vmcnt; body identical to verified ITERP)
  #define ITERQ(tt_, buf, WAITOP)                                             \
    {                                                                         \
      WAITOP;                                                                 \
      __builtin_amdgcn_s_barrier();             /* buf ready */               \
      const char* ca = (const char*)sA + (buf) * 16384;                       \
      const char* cb = (const char*)sB + (buf) * 16384;                       \
      bf16x8 af[4][2], bfr[2][2];                                             \
      _Pragma("unroll")                                                       \
      for (int mi = 0; mi < 4; ++mi)                                          \
        _Pragma("unroll")                                                     \
        for (int ks = 0; ks < 2; ++ks)                                        \
          af[mi][ks] = *reinterpret_cast<const bf16x8*>(                      \
              ca + (wm * 64 + mi * 16 + c) * 128 + (((ks * 4 + g) ^ rk) * 16)); \
      _Pragma("unroll")                                                       \
      for (int ni = 0; ni < 2; ++ni)                                          \
        _Pragma("unroll")                                                     \
        for (int ks = 0; ks < 2; ++ks)                                        \
          bfr[ni][ks] = *reinterpret_cast<const bf16x8*>(                     \
              cb + (wn * 32 + ni * 16 + c) * 128 + (((ks * 4 + g) ^ rk) * 16)); \
      asm volatile("s_waitcnt lgkmcnt(0)" ::: "memory"); /* my reads done */  \
      __builtin_amdgcn_s_barrier();             /* all reads done */          \
      if ((tt_) + 2 < 48) STGQ(buf, (tt_) + 2); /* refill freed buffer */     \
      __builtin_amdgcn_s_setprio(1);                                          \
      _Pragma("unroll")                                                       \
      for (int ks = 0; ks < 2; ++ks)                                          \
        _Pragma("unroll")                                                     \
        for (int mi = 0; mi < 4; ++mi)                                        \
          _Pragma("unroll")                                                   \
          for (int ni = 0; ni < 2; ++ni)                                      \
            acc[mi][ni] = MFMA16(af[mi][ks], bfr[ni][ks], acc[mi][ni]);       \
      __builtin_amdgcn_s_setprio(0);                                          \
    }

  // per-segment scatter epilogue (runtime seg; same verified code), + rezero
  #define EPIQ(segv)                                                          \
    { const int mode = (segv);                                                \
      _Pragma("unroll")                                                       \
      for (int ni = 0; ni < 2; ++ni) {                                        \
        int cm = by * 128 + wn * 32 + ni * 16 + c;                            \
        int h = cm >> 6, d = cm & 63;                                         \
        _Pragma("unroll")                                                     \
        for (int mi = 0; mi < 4; ++mi) {                                      \
          int row0 = bx * 128 + wm * 64 + mi * 16 + g * 4;                    \
          int b = row0 >> 11, tt0 = row0 & 2047;                              \
          if (mode == 2) {                                                    \
            bf16x4 wv;                                                        \
            _Pragma("unroll")                                                 \
            for (int r = 0; r < 4; ++r) wv[r] = (bf16_t)acc[mi][ni][r];       \
            *reinterpret_cast<bf16x4*>(                                       \
                &vto[((size_t)(b * H_ + h) * D_ + d) * T_ + tt0]) = wv;       \
          } else {                                                            \
            bf16_t* dst = (mode == 0) ? qo : ko;                              \
            float   sc  = (mode == 0) ? qscale : 1.0f;                        \
            _Pragma("unroll")                                                 \
            for (int r = 0; r < 4; ++r)                                       \
              dst[((size_t)(b * H_ + h) * T_ + (tt0 + r)) * D_ + d] =         \
                  (bf16_t)(acc[mi][ni][r] * sc);                              \
          }                                                                   \
        }                                                                     \
      }                                                                       \
      _Pragma("unroll")                                                       \
      for (int mi = 0; mi < 4; ++mi)                                          \
        _Pragma("unroll")                                                     \
        for (int ni = 0; ni < 2; ++ni)                                        \
          acc[mi][ni] = (f32x4){0.f, 0.f, 0.f, 0.f};                          \
    }

  #define VM4 asm volatile("s_waitcnt vmcnt(4)" ::: "memory")
  #define VM0 asm volatile("s_waitcnt vmcnt(0)" ::: "memory")

  STGQ(0, 0);                                   // prologue: 2 steps in flight
  STGQ(1, 1);
  #pragma unroll 1
  for (int t2 = 0; t2 < 46; t2 += 2) {
    ITERQ(t2,     0, VM4);
    ITERQ(t2 + 1, 1, VM4);
    if ((t2 & 15) == 14) EPIQ(t2 >> 4);         // t2 = 14 -> seg0, 30 -> seg1
  }
  ITERQ(46, 0, VM4);
  ITERQ(47, 1, VM0);
  EPIQ(2);
  #undef VM0
  #undef VM4
  #undef EPIQ
  #undef ITERQ
  #undef STGQ
}

// ---------------- flash attention (causal) -----------------------------------
// v4 (R11 — best measured): 4-wave blocks, counted-vmcnt K/V pipeline, fixed-m
// softmax (m=8 in QK C-in, exp2 domain, cancels in O=PV/l), in-register
// P^T->B-frag via cvt_pk + permlane swaps (no sP LDS).
__global__ __launch_bounds__(256, 4) void attn_fwd(
    const bf16_t* __restrict__ q, const bf16_t* __restrict__ k,
    const bf16_t* __restrict__ vt, bf16_t* __restrict__ att)
{
  __shared__ bf16_t sK[2][64 * 64], sV[2][64 * 64];   // 16KB + 16KB
  const int tid = threadIdx.x, lane = tid & 63, w = tid >> 6;
  const int g = lane >> 4, c = lane & 15;
  const int bid = blockIdx.x;
  const int qt = 31 - (bid >> 5);                     // longest blocks first
  const int bh = bid & 31;
  const bf16_t* qb = q  + (size_t)bh * T_ * D_;
  const bf16_t* kb = k  + (size_t)bh * T_ * D_;
  const bf16_t* vb = vt + (size_t)bh * D_ * T_;       // vt[d][t]

  // Q fragments straight from global (read once)
  bf16x8 qa[2];
  #pragma unroll
  for (int ks = 0; ks < 2; ++ks)
    qa[ks] = *reinterpret_cast<const bf16x8*>(
        qb + (size_t)(qt * 64 + w * 16 + c) * D_ + ks * 32 + g * 8);

  // stage tile kt into buffer buf: 2 K-loads + 2 V-loads per thread (4 gld16)
  const int srow = tid >> 3, sgr0 = tid & 7;
  #define STAGE(buf, kt)                                                        \
    {                                                                           \
      char* kdst = (char*)sK + (size_t)(buf) * 8192;                            \
      char* vdst = (char*)sV + (size_t)(buf) * 8192;                            \
      _Pragma("unroll")                                                         \
      for (int it = 0; it < 2; ++it) {                                          \
        int idx = it * 256 + tid;                                               \
        int row = it * 32 + srow;                                               \
        int sg  = sgr0 ^ (row & 7);                                             \
        gld16(kb + (size_t)((kt) * 64 + row) * D_ + sg * 8, kdst + idx * 16);   \
        gld16(vb + (size_t)row * T_ + (kt) * 64 + sg * 8,   vdst + idx * 16);   \
      }                                                                         \
    }

  STAGE(0, 0);                                        // prologue: 2 in flight
  if (qt >= 1) STAGE(1, 1);

  float l_r = 0.f;                                    // per-lane l (q = c)
  f32x4 acc_t[4] = {};                                // O^T frags [d-block]
  const int rowK = c & 7;                             // swizzle key per lane

  #pragma unroll 1
  for (int kt = 0; kt <= qt; ++kt) {
    const int cur = kt & 1;
    if (kt < qt) asm volatile("s_waitcnt vmcnt(4)" ::: "memory");
    else         asm volatile("s_waitcnt vmcnt(0)" ::: "memory");
    __builtin_amdgcn_s_barrier();                     // buf[cur] ready

    const char* kc = (char*)sK + (size_t)cur * 8192;
    const char* vc = (char*)sV + (size_t)cur * 8192;
    bf16x8 kf[2][4], vf[2][4];
    #pragma unroll
    for (int ks = 0; ks < 2; ++ks)
      #pragma unroll
      for (int f = 0; f < 4; ++f) {
        int rb = (f * 16 + c) * 128;
        int gsw = ((ks * 4 + g) ^ rowK) * 16;
        kf[ks][f] = *reinterpret_cast<const bf16x8*>(kc + rb + gsw);
        vf[ks][f] = *reinterpret_cast<const bf16x8*>(vc + rb + gsw);
      }
    asm volatile("s_waitcnt lgkmcnt(0)" ::: "memory"); // my reads of buf done
    __builtin_amdgcn_s_barrier();                     // all waves' reads done
    if (kt + 2 <= qt) STAGE(cur, kt + 2);             // refill freed buffer

    // S^T - 8 = K Q^T + (-8): fixed-m softmax, m=8 folded into C-in
    f32x4 s[4];
    #pragma unroll
    for (int fj = 0; fj < 4; ++fj) {
      s[fj][0] = -8.f; s[fj][1] = -8.f; s[fj][2] = -8.f; s[fj][3] = -8.f;
    }
    __builtin_amdgcn_s_setprio(1);
    #pragma unroll
    for (int fj = 0; fj < 4; ++fj)
      #pragma unroll
      for (int ks = 0; ks < 2; ++ks)
        s[fj] = MFMA16(kf[ks][fj], qa[ks], s[fj]);
    __builtin_amdgcn_s_setprio(0);

    if (kt == qt) {                                   // causal mask on diagonal
      #pragma unroll
      for (int fj = 0; fj < 4; ++fj)
        #pragma unroll
        for (int r = 0; r < 4; ++r)
          if (fj * 16 + g * 4 + r > w * 16 + c) s[fj][r] = -1e30f;
    }

    // P = exp2(s); pack to bf16 pairs; tree-summed l (1 dependent add)
    unsigned pk[4][2];
    float ls[4];
    #pragma unroll
    for (int fj = 0; fj < 4; ++fj) {
      float pe0 = __builtin_amdgcn_exp2f(s[fj][0]);
      float pe1 = __builtin_amdgcn_exp2f(s[fj][1]);
      float pe2 = __builtin_amdgcn_exp2f(s[fj][2]);
      float pe3 = __builtin_amdgcn_exp2f(s[fj][3]);
      ls[fj] = (pe0 + pe1) + (pe2 + pe3);
      asm("v_cvt_pk_bf16_f32 %0, %1, %2" : "=v"(pk[fj][0]) : "v"(pe0), "v"(pe1));
      asm("v_cvt_pk_bf16_f32 %0, %1, %2" : "=v"(pk[fj][1]) : "v"(pe2), "v"(pe3));
    }
    l_r += (ls[0] + ls[1]) + (ls[2] + ls[3]);

    // in-register P^T -> B-frag redistribution (replaces sP LDS round-trip)
    bf16x8 pf[2];
    #pragma unroll
    for (int ks = 0; ks < 2; ++ks) {
      unsigned x0 = pk[2 * ks][0], y0 = pk[2 * ks + 1][0];
      unsigned x1 = pk[2 * ks][1], y1 = pk[2 * ks + 1][1];
      asm("v_permlane32_swap_b32 %0, %1" : "+v"(x0), "+v"(y0));
      asm("v_permlane32_swap_b32 %0, %1" : "+v"(x1), "+v"(y1));
      asm("v_permlane16_swap_b32 %0, %1" : "+v"(x0), "+v"(y0));
      asm("v_permlane16_swap_b32 %0, %1" : "+v"(x1), "+v"(y1));
      u32x4 t; t[0] = x0; t[1] = x1; t[2] = y0; t[3] = y1;
      pf[ks] = __builtin_bit_cast(bf16x8, t);
    }

    // O^T += V^T P^T
    __builtin_amdgcn_s_setprio(1);
    #pragma unroll
    for (int fd = 0; fd < 4; ++fd)
      #pragma unroll
      for (int ks = 0; ks < 2; ++ks)
        acc_t[fd] = MFMA16(vf[ks][fd], pf[ks], acc_t[fd]);
    __builtin_amdgcn_s_setprio(0);
  }

  // deferred l reduce across the 4 g-groups, then write O
  l_r += __shfl_xor(l_r, 16);
  l_r += __shfl_xor(l_r, 32);
  float inv = 1.0f / l_r;
  const int b = bh >> 4, h = bh & 15;
  const int t = qt * 64 + w * 16 + c;
  #pragma unroll
  for (int fd = 0; fd < 4; ++fd) {
    bf16x4 wv;
    #pragma unroll
    for (int r = 0; r < 4; ++r) wv[r] = (bf16_t)(acc_t[fd][r] * inv);
    int d = fd * 16 + g * 4;
    *reinterpret_cast<bf16x4*>(&att[((size_t)(b * T_ + t) * H_ + h) * D_ + d]) = wv;
  }
  #undef STAGE
}

// ---------------- output projection: out = att @ Wp^T + bp (fp32 out) --------
__global__ __launch_bounds__(512, 2) void gemm_proj(
    const bf16_t* __restrict__ attb, const bf16_t* __restrict__ Wpb,
    const float* __restrict__ bp, float* __restrict__ out)
{
  __shared__ bf16_t sA[2][128 * 64];            // 32 KB
  __shared__ bf16_t sB[2][128 * 64];            // 32 KB
  f32x4 acc[4][2] = {};
  const int bx = blockIdx.x, by = blockIdx.y;
  gemm128_core(attb, Wpb, &sA[0][0], &sB[0][0], acc, bx, by);

  const int tid = threadIdx.x, lane = tid & 63, wid = tid >> 6;
  const int wm = wid >> 2, wn = wid & 3;
  const int g = lane >> 4, c = lane & 15;
  #pragma unroll
  for (int m = 0; m < 4; ++m)
    #pragma unroll
    for (int n = 0; n < 2; ++n)
      #pragma unroll
      for (int r = 0; r < 4; ++r) {
        int row = bx * 128 + wm * 64 + m * 16 + g * 4 + r;
        int col = by * 128 + wn * 32 + n * 16 + c;
        out[(size_t)row * C_ + col] = acc[m][n][r] + bp[col];
      }
}

extern "C" void kernel_launch(void* const* d_in, const int* in_sizes, int n_in,
                              void* d_out, int out_size, void* d_ws, size_t ws_size,
                              hipStream_t stream)
{
  const float* X  = (const float*)d_in[0];
  const float* Wq = (const float*)d_in[1];
  const float* Wk = (const float*)d_in[2];
  const float* Wv = (const float*)d_in[3];
  const float* Wp = (const float*)d_in[4];
  const float* bp = (const float*)d_in[5];
  float* out = (float*)d_out;

  char* ws = (char*)d_ws;
  bf16_t* Xb   = (bf16_t*)(ws);                       // 8 MB  [B*T][C]
  bf16_t* Wqb  = (bf16_t*)(ws + ((size_t)8  << 20));  // 2 MB  (Wq|Wk|Wv contiguous = Wqkv [3072][1024])
  bf16_t* Wkb  = (bf16_t*)(ws + ((size_t)10 << 20));  // 2 MB
  bf16_t* Wvb  = (bf16_t*)(ws + ((size_t)12 << 20));  // 2 MB
  bf16_t* Wpb  = (bf16_t*)(ws + ((size_t)14 << 20));  // 2 MB
  bf16_t* qo   = (bf16_t*)(ws + ((size_t)16 << 20));  // 8 MB  [B,H,T,D] (pre-scaled, exp2 domain)
  bf16_t* ko   = (bf16_t*)(ws + ((size_t)24 << 20));  // 8 MB  [B,H,T,D]
  bf16_t* vto  = (bf16_t*)(ws + ((size_t)32 << 20));  // 8 MB  [B,H,D,T]
  bf16_t* attb = (bf16_t*)(ws + ((size_t)40 << 20));  // 8 MB  [B,T,H*D]

  cast_all<<<8192, 256, 0, stream>>>(X, Wq, Wk, Wv, Wp, Xb, Wqb, Wkb, Wvb, Wpb);
  gemm_qkv<<<dim3(32, 8), 512, 0, stream>>>(Xb, Wqb, qo, ko, vto);
  attn_fwd<<<1024, 256, 0, stream>>>(qo, ko, vto, attb);
  gemm_proj<<<dim3(32, 8), 512, 0, stream>>>(attb, Wpb, bp, out);
}

// Round 16
// 87.747 us; speedup vs baseline: 1.0606x; 1.0606x over previous
//
#include <hip/hip_runtime.h>
#include <hip/hip_bf16.h>

typedef __bf16 bf16_t;
typedef __bf16 bf16x8 __attribute__((ext_vector_type(8)));
typedef __bf16 bf16x4 __attribute__((ext_vector_type(4)));
typedef float  f32x4  __attribute__((ext_vector_type(4)));
typedef unsigned int u32x4 __attribute__((ext_vector_type(4)));

#define MFMA16(a,b,c) __builtin_amdgcn_mfma_f32_16x16x32_bf16(a,b,c,0,0,0)

constexpr int B_ = 2, T_ = 2048, H_ = 16, D_ = 64, C_ = 1024;
constexpr int GK = C_;          // GEMM K dim (1024)

// async global->LDS, 16B per lane. LDS dest: wave-uniform base + lane*16.
typedef const __attribute__((address_space(1))) unsigned char ga_t;
typedef __attribute__((address_space(3))) unsigned char la_t;
__device__ __forceinline__ void gld16(const void* g, void* l) {
  __builtin_amdgcn_global_load_lds((ga_t*)g, (la_t*)l, 16, 0, 0);
}

// ---------------- cast fp32 -> bf16 (X, Wq, Wk, Wv, Wp) ----------------
__global__ __launch_bounds__(256) void cast_all(
    const float* __restrict__ X,  const float* __restrict__ Wq,
    const float* __restrict__ Wk, const float* __restrict__ Wv,
    const float* __restrict__ Wp,
    bf16_t* __restrict__ Xb,  bf16_t* __restrict__ Wqb, bf16_t* __restrict__ Wkb,
    bf16_t* __restrict__ Wvb, bf16_t* __restrict__ Wpb)
{
  int i = blockIdx.x * 256 + threadIdx.x;   // each thread converts 4 floats
  const float* src; bf16_t* dst; int off;
  if      (i < 1048576) { src = X;  dst = Xb;  off = i; }
  else if (i < 1310720) { src = Wq; dst = Wqb; off = i - 1048576; }
  else if (i < 1572864) { src = Wk; dst = Wkb; off = i - 1310720; }
  else if (i < 1835008) { src = Wv; dst = Wvb; off = i - 1572864; }
  else                  { src = Wp; dst = Wpb; off = i - 1835008; }
  float4 v = *reinterpret_cast<const float4*>(src + (size_t)off * 4);
  bf16x4 o;
  o[0] = (bf16_t)v.x; o[1] = (bf16_t)v.y; o[2] = (bf16_t)v.z; o[3] = (bf16_t)v.w;
  *reinterpret_cast<bf16x4*>(dst + (size_t)off * 4) = o;
}

// =============================================================================
// 2-phase 128x128 BK=64 counted-vmcnt GEMM core (R11 — best measured, frozen).
// =============================================================================
__device__ __forceinline__ void gemm128_core(
    const bf16_t* __restrict__ A, const bf16_t* __restrict__ Bw,
    bf16_t* sA, bf16_t* sB, f32x4 (&acc)[4][2], int bx, int by)
{
  const int tid = threadIdx.x, lane = tid & 63, wid = tid >> 6;
  const int wm = wid >> 2, wn = wid & 3;
  const int g = lane >> 4, c = lane & 15, rk = c & 7;
  const int srow = tid >> 3;                    // 0..63 rows per 64-row slab
  const int sg   = (tid & 7) ^ (srow & 7);      // pre-swizzled source granule
  const bf16_t* asrc = A  + (size_t)(bx * 128 + srow) * GK + sg * 8;
  const bf16_t* bsrc = Bw + (size_t)(by * 128 + srow) * GK + sg * 8;

  #define STGP(buf, kt)                                                       \
    { char* da = (char*)sA + (buf) * 16384;                                   \
      char* db = (char*)sB + (buf) * 16384;                                   \
      _Pragma("unroll")                                                       \
      for (int it = 0; it < 2; ++it) {                                        \
        gld16(asrc + (size_t)it * 65536 + (kt) * 64, da + (it * 512 + tid) * 16); \
        gld16(bsrc + (size_t)it * 65536 + (kt) * 64, db + (it * 512 + tid) * 16); \
      } }

  #define ITERP(t, buf)                                                       \
    {                                                                         \
      if ((t) < 15) asm volatile("s_waitcnt vmcnt(4)" ::: "memory");          \
      else          asm volatile("s_waitcnt vmcnt(0)" ::: "memory");          \
      __builtin_amdgcn_s_barrier();             /* buf[cur] ready */          \
      const char* ca = (const char*)sA + (buf) * 16384;                       \
      const char* cb = (const char*)sB + (buf) * 16384;                       \
      bf16x8 af[4][2], bfr[2][2];                                             \
      _Pragma("unroll")                                                       \
      for (int mi = 0; mi < 4; ++mi)                                          \
        _Pragma("unroll")                                                     \
        for (int ks = 0; ks < 2; ++ks)                                        \
          af[mi][ks] = *reinterpret_cast<const bf16x8*>(                      \
              ca + (wm * 64 + mi * 16 + c) * 128 + (((ks * 4 + g) ^ rk) * 16)); \
      _Pragma("unroll")                                                       \
      for (int ni = 0; ni < 2; ++ni)                                          \
        _Pragma("unroll")                                                     \
        for (int ks = 0; ks < 2; ++ks)                                        \
          bfr[ni][ks] = *reinterpret_cast<const bf16x8*>(                     \
              cb + (wn * 32 + ni * 16 + c) * 128 + (((ks * 4 + g) ^ rk) * 16)); \
      asm volatile("s_waitcnt lgkmcnt(0)" ::: "memory"); /* my reads done */  \
      __builtin_amdgcn_s_barrier();             /* all reads done */          \
      if ((t) + 2 < 16) STGP(buf, (t) + 2);     /* refill freed buffer */     \
      __builtin_amdgcn_s_setprio(1);                                          \
      _Pragma("unroll")                                                       \
      for (int ks = 0; ks < 2; ++ks)                                          \
        _Pragma("unroll")                                                     \
        for (int mi = 0; mi < 4; ++mi)                                        \
          _Pragma("unroll")                                                   \
          for (int ni = 0; ni < 2; ++ni)                                      \
            acc[mi][ni] = MFMA16(af[mi][ks], bfr[ni][ks], acc[mi][ni]);       \
      __builtin_amdgcn_s_setprio(0);                                          \
    }

  STGP(0, 0);                                   // prologue: 2 tiles in flight
  STGP(1, 1);
  #pragma unroll 1
  for (int t0 = 0; t0 < 16; t0 += 2) {
    ITERP(t0, 0);
    ITERP(t0 + 1, 1);
  }
  #undef ITERP
  #undef STGP
}

// ---------------- fused QKV projection: C[4096,3072] = Xb @ Wqkv^T -----------
// 128x128 tile (R11 config — best measured, frozen), grid 32x24 = 768 blocks.
__global__ __launch_bounds__(512, 2) void gemm_qkv(
    const bf16_t* __restrict__ Xb, const bf16_t* __restrict__ Wqkv,
    bf16_t* __restrict__ qo, bf16_t* __restrict__ ko, bf16_t* __restrict__ vto)
{
  __shared__ bf16_t sA[2][128 * 64];            // 32 KB
  __shared__ bf16_t sB[2][128 * 64];            // 32 KB
  f32x4 acc[4][2] = {};
  const int bx = blockIdx.x, by = blockIdx.y;
  gemm128_core(Xb, Wqkv, &sA[0][0], &sB[0][0], acc, bx, by);

  const int tid = threadIdx.x, lane = tid & 63, wid = tid >> 6;
  const int wm = wid >> 2, wn = wid & 3;
  const int g = lane >> 4, c = lane & 15;
  const float qscale = 0.04508422002778f;       // log2(e) * 1024^-0.5
  const int mode = by >> 3;                     // 0=q, 1=k, 2=v (block-uniform)
  #pragma unroll
  for (int ni = 0; ni < 2; ++ni) {
    int col = by * 128 + wn * 32 + ni * 16 + c;
    int cm  = col & 1023;
    int h = cm >> 6, d = cm & 63;
    #pragma unroll
    for (int mi = 0; mi < 4; ++mi) {
      int row0 = bx * 128 + wm * 64 + mi * 16 + g * 4;
      int b = row0 >> 11, tt0 = row0 & 2047;
      if (mode == 2) {                          // v: [b,h,d,t] -> t contiguous
        bf16x4 wv;
        #pragma unroll
        for (int r = 0; r < 4; ++r) wv[r] = (bf16_t)acc[mi][ni][r];
        *reinterpret_cast<bf16x4*>(
            &vto[((size_t)(b * H_ + h) * D_ + d) * T_ + tt0]) = wv;
      } else {
        bf16_t* dst = (mode == 0) ? qo : ko;
        float   sc  = (mode == 0) ? qscale : 1.0f;
        #pragma unroll
        for (int r = 0; r < 4; ++r)
          dst[((size_t)(b * H_ + h) * T_ + (tt0 + r)) * D_ + d] =
              (bf16_t)(acc[mi][ni][r] * sc);
      }
    }
  }
}

// ---------------- flash attention (causal), paired Q-tiles --------------------
// v5: complementary Q-tile pairing for load balance WITHOUT extra traffic
// (R13 lesson: partials round-trip ate the balance gain). Block (p, bh),
// p=0..15: processes Q-tiles qtA=31-p AND qtB=p over ONE KV sweep kt=0..qtA.
// Compute units/block = (qtA+1)+(qtB+1) = 33, uniform across all 512 blocks;
// staging total drops 26% (12544 vs 16896 tiles); kf/vf regs serve both tiles
// when kt<=qtB. B-branch is wave-uniform. Per-tile softmax/PV = verified v4
// code (fixed-m m=8 in C-in, exp2 domain, cvt_pk+permlane P^T->B-frag).
// Grid 512 @ 2 blk/CU = one uniform round (matches measured ~26% occupancy).
__global__ __launch_bounds__(256, 2) void attn_fwd(
    const bf16_t* __restrict__ q, const bf16_t* __restrict__ k,
    const bf16_t* __restrict__ vt, bf16_t* __restrict__ att)
{
  __shared__ bf16_t sK[2][64 * 64], sV[2][64 * 64];   // 16KB + 16KB
  const int tid = threadIdx.x, lane = tid & 63, w = tid >> 6;
  const int g = lane >> 4, c = lane & 15;
  const int bid = blockIdx.x;
  const int p  = bid >> 5;                            // 0..15 (heaviest first)
  const int bh = bid & 31;
  const int qtA = 31 - p, qtB = p;
  const bf16_t* qb = q  + (size_t)bh * T_ * D_;
  const bf16_t* kb = k  + (size_t)bh * T_ * D_;
  const bf16_t* vb = vt + (size_t)bh * D_ * T_;       // vt[d][t]

  // Q fragments for both tiles (read once)
  bf16x8 qaA[2], qaB[2];
  #pragma unroll
  for (int ks = 0; ks < 2; ++ks) {
    qaA[ks] = *reinterpret_cast<const bf16x8*>(
        qb + (size_t)(qtA * 64 + w * 16 + c) * D_ + ks * 32 + g * 8);
    qaB[ks] = *reinterpret_cast<const bf16x8*>(
        qb + (size_t)(qtB * 64 + w * 16 + c) * D_ + ks * 32 + g * 8);
  }

  // stage tile kt into buffer buf: 2 K-loads + 2 V-loads per thread (4 gld16)
  const int srow = tid >> 3, sgr0 = tid & 7;
  #define STAGE(buf, kt)                                                        \
    {                                                                           \
      char* kdst = (char*)sK + (size_t)(buf) * 8192;                            \
      char* vdst = (char*)sV + (size_t)(buf) * 8192;                            \
      _Pragma("unroll")                                                         \
      for (int it = 0; it < 2; ++it) {                                          \
        int idx = it * 256 + tid;                                               \
        int row = it * 32 + srow;                                               \
        int sg  = sgr0 ^ (row & 7);                                             \
        gld16(kb + (size_t)((kt) * 64 + row) * D_ + sg * 8, kdst + idx * 16);   \
        gld16(vb + (size_t)row * T_ + (kt) * 64 + sg * 8,   vdst + idx * 16);   \
      }                                                                         \
    }

  // one tile's softmax+PV given shared kf/vf (verified v4 body)
  #define PROC(qa_, acc_, l_, diag)                                             \
    {                                                                           \
      f32x4 s[4];                                                               \
      _Pragma("unroll")                                                         \
      for (int fj = 0; fj < 4; ++fj) {                                          \
        s[fj][0] = -8.f; s[fj][1] = -8.f; s[fj][2] = -8.f; s[fj][3] = -8.f;     \
      }                                                                         \
      __builtin_amdgcn_s_setprio(1);                                            \
      _Pragma("unroll")                                                         \
      for (int fj = 0; fj < 4; ++fj)                                            \
        _Pragma("unroll")                                                       \
        for (int ks = 0; ks < 2; ++ks)                                          \
          s[fj] = MFMA16(kf[ks][fj], qa_[ks], s[fj]);                           \
      __builtin_amdgcn_s_setprio(0);                                            \
      if (diag) {                                                               \
        _Pragma("unroll")                                                       \
        for (int fj = 0; fj < 4; ++fj)                                          \
          _Pragma("unroll")                                                     \
          for (int r = 0; r < 4; ++r)                                           \
            if (fj * 16 + g * 4 + r > w * 16 + c) s[fj][r] = -1e30f;            \
      }                                                                         \
      unsigned pk[4][2];                                                        \
      float ls[4];                                                              \
      _Pragma("unroll")                                                         \
      for (int fj = 0; fj < 4; ++fj) {                                          \
        float pe0 = __builtin_amdgcn_exp2f(s[fj][0]);                           \
        float pe1 = __builtin_amdgcn_exp2f(s[fj][1]);                           \
        float pe2 = __builtin_amdgcn_exp2f(s[fj][2]);                           \
        float pe3 = __builtin_amdgcn_exp2f(s[fj][3]);                           \
        ls[fj] = (pe0 + pe1) + (pe2 + pe3);                                     \
        asm("v_cvt_pk_bf16_f32 %0, %1, %2" : "=v"(pk[fj][0]) : "v"(pe0), "v"(pe1)); \
        asm("v_cvt_pk_bf16_f32 %0, %1, %2" : "=v"(pk[fj][1]) : "v"(pe2), "v"(pe3)); \
      }                                                                         \
      l_ += (ls[0] + ls[1]) + (ls[2] + ls[3]);                                  \
      bf16x8 pf[2];                                                             \
      _Pragma("unroll")                                                         \
      for (int ks = 0; ks < 2; ++ks) {                                          \
        unsigned x0 = pk[2 * ks][0], y0 = pk[2 * ks + 1][0];                    \
        unsigned x1 = pk[2 * ks][1], y1 = pk[2 * ks + 1][1];                    \
        asm("v_permlane32_swap_b32 %0, %1" : "+v"(x0), "+v"(y0));               \
        asm("v_permlane32_swap_b32 %0, %1" : "+v"(x1), "+v"(y1));               \
        asm("v_permlane16_swap_b32 %0, %1" : "+v"(x0), "+v"(y0));               \
        asm("v_permlane16_swap_b32 %0, %1" : "+v"(x1), "+v"(y1));               \
        u32x4 t; t[0] = x0; t[1] = x1; t[2] = y0; t[3] = y1;                    \
        pf[ks] = __builtin_bit_cast(bf16x8, t);                                 \
      }                                                                         \
      __builtin_amdgcn_s_setprio(1);                                            \
      _Pragma("unroll")                                                         \
      for (int fd = 0; fd < 4; ++fd)                                            \
        _Pragma("unroll")                                                       \
        for (int ks = 0; ks < 2; ++ks)                                          \
          acc_[fd] = MFMA16(vf[ks][fd], pf[ks], acc_[fd]);                      \
      __builtin_amdgcn_s_setprio(0);                                            \
    }

  STAGE(0, 0);                                        // prologue: 2 in flight
  STAGE(1, 1);                                        // qtA >= 16 always

  float lA = 0.f, lB = 0.f;
  f32x4 accA[4] = {}, accB[4] = {};
  const int rowK = c & 7;                             // swizzle key per lane

  #pragma unroll 1
  for (int kt = 0; kt <= qtA; ++kt) {
    const int cur = kt & 1;
    if (kt < qtA) asm volatile("s_waitcnt vmcnt(4)" ::: "memory");
    else          asm volatile("s_waitcnt vmcnt(0)" ::: "memory");
    __builtin_amdgcn_s_barrier();                     // buf[cur] ready

    const char* kc = (char*)sK + (size_t)cur * 8192;
    const char* vc = (char*)sV + (size_t)cur * 8192;
    bf16x8 kf[2][4], vf[2][4];
    #pragma unroll
    for (int ks = 0; ks < 2; ++ks)
      #pragma unroll
      for (int f = 0; f < 4; ++f) {
        int rb = (f * 16 + c) * 128;
        int gsw = ((ks * 4 + g) ^ rowK) * 16;
        kf[ks][f] = *reinterpret_cast<const bf16x8*>(kc + rb + gsw);
        vf[ks][f] = *reinterpret_cast<const bf16x8*>(vc + rb + gsw);
      }
    asm volatile("s_waitcnt lgkmcnt(0)" ::: "memory"); // my reads of buf done
    __builtin_amdgcn_s_barrier();                     // all waves' reads done
    if (kt + 2 <= qtA) STAGE(cur, kt + 2);            // refill freed buffer

    PROC(qaA, accA, lA, kt == qtA)                    // tile A: always
    if (kt <= qtB) PROC(qaB, accB, lB, kt == qtB)     // tile B: wave-uniform
  }

  // epilogue: reduce l across g-groups + write both tiles
  const int b = bh >> 4, h = bh & 15;
  lA += __shfl_xor(lA, 16); lA += __shfl_xor(lA, 32);
  lB += __shfl_xor(lB, 16); lB += __shfl_xor(lB, 32);
  float invA = 1.0f / lA, invB = 1.0f / lB;
  const int tA = qtA * 64 + w * 16 + c;
  const int tB = qtB * 64 + w * 16 + c;
  #pragma unroll
  for (int fd = 0; fd < 4; ++fd) {
    bf16x4 wvA, wvB;
    #pragma unroll
    for (int r = 0; r < 4; ++r) {
      wvA[r] = (bf16_t)(accA[fd][r] * invA);
      wvB[r] = (bf16_t)(accB[fd][r] * invB);
    }
    int d = fd * 16 + g * 4;
    *reinterpret_cast<bf16x4*>(&att[((size_t)(b * T_ + tA) * H_ + h) * D_ + d]) = wvA;
    *reinterpret_cast<bf16x4*>(&att[((size_t)(b * T_ + tB) * H_ + h) * D_ + d]) = wvB;
  }
  #undef PROC
  #undef STAGE
}

// ---------------- output projection: out = att @ Wp^T + bp (fp32 out) --------
__global__ __launch_bounds__(512, 2) void gemm_proj(
    const bf16_t* __restrict__ attb, const bf16_t* __restrict__ Wpb,
    const float* __restrict__ bp, float* __restrict__ out)
{
  __shared__ bf16_t sA[2][128 * 64];            // 32 KB
  __shared__ bf16_t sB[2][128 * 64];            // 32 KB
  f32x4 acc[4][2] = {};
  const int bx = blockIdx.x, by = blockIdx.y;
  gemm128_core(attb, Wpb, &sA[0][0], &sB[0][0], acc, bx, by);

  const int tid = threadIdx.x, lane = tid & 63, wid = tid >> 6;
  const int wm = wid >> 2, wn = wid & 3;
  const int g = lane >> 4, c = lane & 15;
  #pragma unroll
  for (int m = 0; m < 4; ++m)
    #pragma unroll
    for (int n = 0; n < 2; ++n)
      #pragma unroll
      for (int r = 0; r < 4; ++r) {
        int row = bx * 128 + wm * 64 + m * 16 + g * 4 + r;
        int col = by * 128 + wn * 32 + n * 16 + c;
        out[(size_t)row * C_ + col] = acc[m][n][r] + bp[col];
      }
}

extern "C" void kernel_launch(void* const* d_in, const int* in_sizes, int n_in,
                              void* d_out, int out_size, void* d_ws, size_t ws_size,
                              hipStream_t stream)
{
  const float* X  = (const float*)d_in[0];
  const float* Wq = (const float*)d_in[1];
  const float* Wk = (const float*)d_in[2];
  const float* Wv = (const float*)d_in[3];
  const float* Wp = (const float*)d_in[4];
  const float* bp = (const float*)d_in[5];
  float* out = (float*)d_out;

  char* ws = (char*)d_ws;
  bf16_t* Xb   = (bf16_t*)(ws);                       // 8 MB  [B*T][C]
  bf16_t* Wqb  = (bf16_t*)(ws + ((size_t)8  << 20));  // 2 MB  (Wq|Wk|Wv contiguous = Wqkv [3072][1024])
  bf16_t* Wkb  = (bf16_t*)(ws + ((size_t)10 << 20));  // 2 MB
  bf16_t* Wvb  = (bf16_t*)(ws + ((size_t)12 << 20));  // 2 MB
  bf16_t* Wpb  = (bf16_t*)(ws + ((size_t)14 << 20));  // 2 MB
  bf16_t* qo   = (bf16_t*)(ws + ((size_t)16 << 20));  // 8 MB  [B,H,T,D] (pre-scaled, exp2 domain)
  bf16_t* ko   = (bf16_t*)(ws + ((size_t)24 << 20));  // 8 MB  [B,H,T,D]
  bf16_t* vto  = (bf16_t*)(ws + ((size_t)32 << 20));  // 8 MB  [B,H,D,T]
  bf16_t* attb = (bf16_t*)(ws + ((size_t)40 << 20));  // 8 MB  [B,T,H*D]

  cast_all<<<8192, 256, 0, stream>>>(X, Wq, Wk, Wv, Wp, Xb, Wqb, Wkb, Wvb, Wpb);
  gemm_qkv<<<dim3(32, 24), 512, 0, stream>>>(Xb, Wqb, qo, ko, vto);
  attn_fwd<<<512, 256, 0, stream>>>(qo, ko, vto, attb);
  gemm_proj<<<dim3(32, 8), 512, 0, stream>>>(attb, Wpb, bp, out);
}